// Round 9
// baseline (65.483 us; speedup 1.0000x reference)
//
#include <hip/hip_runtime.h>
#include <hip/hip_fp16.h>

typedef __attribute__((ext_vector_type(8))) _Float16 half8;
typedef __attribute__((ext_vector_type(4))) float f32x4;

// DPP rotate-reduce within each 16-lane row: after ror 1,2,4,8 all 16 lanes
// hold the group sum. Validated numerically in R6/R7/R8.
template <int CTRL>
__device__ __forceinline__ float dpp_ror_add(float p) {
  int s = __builtin_amdgcn_update_dpp(0, __float_as_int(p), CTRL, 0xF, 0xF, true);
  return p + __int_as_float(s);
}

__device__ __forceinline__ unsigned int pack_f16x2(float a, float b) {
  __half2 h = __floats2half2_rn(a, b);  // .x (low) = a
  return *reinterpret_cast<unsigned int*>(&h);
}

// relu on 8 packed f16 via guaranteed v_pk_max_f16 (ternary lowers to
// cmp+cndmask = 3x the VALU; this stays 4 ops). max(x, +0) == relu, no NaNs.
__device__ __forceinline__ half8 relu8(half8 v) {
  union {
    half8 h8;
    unsigned int u[4];
  } a;
  a.h8 = v;
  unsigned int z = 0;  // both f16 halves = +0.0
#pragma unroll
  for (int e = 0; e < 4; ++e)
    asm("v_pk_max_f16 %0, %1, %2" : "=v"(a.u[e]) : "v"(a.u[e]), "v"(z));
  return a.h8;
}

// ---------------------------------------------------------------------------
// Precompute (fp32 math, f16 outputs, packed as uint pairs):
//   hx2[512][128] uint = f16 pairs of x @ W1[:128]
//   hy2[512][128] uint = f16 pairs of y @ W1[128:] + b1
//   W2T2[n][128]  uint = f16 pairs of W2[k][n] (transposed)
// grid 384 x 256 thr: b<64 hx | b<128 hy | b<384 W2T
// ---------------------------------------------------------------------------
__global__ void k_pre(const float* __restrict__ x, const float* __restrict__ y,
                      const float* __restrict__ W1, const float* __restrict__ b1,
                      const float* __restrict__ W2,
                      unsigned int* __restrict__ hx2, unsigned int* __restrict__ hy2,
                      unsigned int* __restrict__ W2T2) {
  const int b = blockIdx.x;
  const int t = threadIdx.x;
  if (b < 128) {
    const bool isx = (b < 64);
    const int i0 = (isx ? b : (b - 64)) * 8;
    const float* __restrict__ src = isx ? x : y;
    const float* __restrict__ W = W1 + (isx ? 0 : 128 * 256);
    float acc[8];
    const float binit = isx ? 0.0f : b1[t];
#pragma unroll
    for (int r = 0; r < 8; ++r) acc[r] = binit;
#pragma unroll 4
    for (int d = 0; d < 128; ++d) {
      const float wv = W[d * 256 + t];  // coalesced across t
#pragma unroll
      for (int r = 0; r < 8; ++r) acc[r] += src[(i0 + r) * 128 + d] * wv;  // uniform loads
    }
    unsigned int* __restrict__ dst = isx ? hx2 : hy2;
#pragma unroll
    for (int r = 0; r < 8; ++r) {
      const float o = __shfl_xor(acc[r], 1, 64);
      if (!(t & 1)) dst[(i0 + r) * 128 + (t >> 1)] = pack_f16x2(acc[r], o);
    }
  } else {
    const int n = b - 128;
    const float wv = W2[t * 256 + n];
    const float o = __shfl_xor(wv, 1, 64);
    if (!(t & 1)) W2T2[n * 128 + (t >> 1)] = pack_f16x2(wv, o);
  }
}

// ---------------------------------------------------------------------------
// Main fused kernel, v9: 16 waves/block (1024 thr), 4 waves/SIMD, 128-reg cap.
// Grid = 512 (ig 0..63 x j-tile 0..7); block = 8 i's x 64 j's x N=256.
// Wave w = (rh = w>>3, cq = w&7): rows rh*32 + mf*16 (mf=2), cols cq*32 +
// nf*16 (nf=2). Persistent regs: bq[8][2] half8 = 64 (B-frags), acc[2][2]=16.
// hy tile lives in LDS (32 KB), staged ONCE, slot-XOR swizzled:
//   slot = kk*4+l4 (16B units), slot' = slot ^ ((row&7)<<2)
//   -> uniform bank phases; dup lanes (l15 vs l15+8) 2-way only.
// Per g (NO barriers): 8 kk x { 1 broadcast hx read + 2 swizzled hy reads +
//   pk_add/pk_max A-build in-register + 4 MFMA f16 }, then epilogue:
//   relu(acc+b2).W3 over nf, DPP 16-lane reduce, cndmask select, 1 LDS write.
// Two __syncthreads total. Final: 512 thr sum 8 cq-partials, coalesced store.
// MFMA f16 frag layout (verified R1/R7/R8):
//   A: row=l15, k=8*l4+e ; B: col=l15, k=8*l4+e ; C: col=l15, row=4*l4+reg
// ---------------------------------------------------------------------------
__launch_bounds__(1024, 4)
__global__ void k_main(const unsigned int* __restrict__ hx2,
                       const unsigned int* __restrict__ hy2,
                       const unsigned int* __restrict__ W2T2,
                       const float* __restrict__ b2, const float* __restrict__ W3,
                       const float* __restrict__ b3, float* __restrict__ out) {
  __shared__ unsigned int hxL[8 * 128];                            // 4 KB
  __shared__ __attribute__((aligned(16))) _Float16 hyL[64 * 256];  // 32 KB
  __shared__ float red[8 * 8 * 64];                                // 16 KB

  const int tid = threadIdx.x;
  const int lane = tid & 63;
  const int w = tid >> 6;        // 0..15
  const int l15 = lane & 15;
  const int l4 = lane >> 4;
  const int rh = w >> 3;         // row-half: rows rh*32..+31
  const int cq = w & 7;          // col slice: cols cq*32..+31
  const int ig = blockIdx.x >> 3;
  const int j0 = (blockIdx.x & 7) * 64;
  const int i0 = ig * 8;

  // ---- stage hxL: 8 rows x 128 uint = 1024 uint, 1 per thread ----
  hxL[tid] = hx2[i0 * 128 + tid];

  // ---- stage hyL (swizzled): thread -> row = tid>>4, slots (tid&15)*2, +1 ----
  {
    const int row = tid >> 4;
    const int s0 = (tid & 15) * 2;
    const unsigned int* src = &hy2[(j0 + row) * 128 + s0 * 4];
    const uint4 v0 = *reinterpret_cast<const uint4*>(src);
    const uint4 v1 = *reinterpret_cast<const uint4*>(src + 4);
    const int sw = (row & 7) << 2;
    *reinterpret_cast<uint4*>(&hyL[row * 256 + ((s0) ^ sw) * 8]) = v0;
    *reinterpret_cast<uint4*>(&hyL[row * 256 + ((s0 + 1) ^ sw) * 8]) = v1;
  }

  // ---- persistent B fragments: col = cq*32+nf*16+l15, k = kk*32+l4*8 ----
  half8 bq[8][2];
  {
    const unsigned int* bb = W2T2 + (cq * 32 + l15) * 128 + l4 * 4;
#pragma unroll
    for (int nf = 0; nf < 2; ++nf)
#pragma unroll
      for (int kk = 0; kk < 8; ++kk)
        bq[kk][nf] = *reinterpret_cast<const half8*>(bb + nf * 16 * 128 + kk * 16);
  }

  // ---- epilogue constants ----
  float b2v[2], w3v[2];
#pragma unroll
  for (int nf = 0; nf < 2; ++nf) {
    b2v[nf] = b2[cq * 32 + nf * 16 + l15];
    w3v[nf] = W3[cq * 32 + nf * 16 + l15];
  }
  const float b3v = b3[0];

  __syncthreads();  // hxL + hyL ready

  // hy read geometry: row0 = rh*32 + l15 (mf=0), row1 = row0 + 16 (mf=1).
  // (row&7) == (l15&7) for both -> shared swizzle; row1 read = row0 + 4096 f16.
  const int swz = (l15 & 7) << 2;
  const _Float16* __restrict__ hyr = &hyL[(rh * 32 + l15) * 256];

#pragma unroll 1
  for (int g = 0; g < 8; ++g) {
    f32x4 acc[2][2];
#pragma unroll
    for (int mf = 0; mf < 2; ++mf)
#pragma unroll
      for (int nf = 0; nf < 2; ++nf) acc[mf][nf] = (f32x4){0.f, 0.f, 0.f, 0.f};

    const unsigned int* __restrict__ hxg = &hxL[g * 128];
#pragma unroll
    for (int kk = 0; kk < 8; ++kk) {
      const half8 hx8 = *reinterpret_cast<const half8*>(hxg + kk * 16 + l4 * 4);
      const int sl = ((kk * 4 + l4) ^ swz) * 8;
      const half8 hy0 = *reinterpret_cast<const half8*>(hyr + sl);
      const half8 hy1 = *reinterpret_cast<const half8*>(hyr + 4096 + sl);
      const half8 af0 = relu8(hy0 + hx8);  // v_pk_add + v_pk_max
      const half8 af1 = relu8(hy1 + hx8);
      __builtin_amdgcn_s_setprio(1);
      acc[0][0] = __builtin_amdgcn_mfma_f32_16x16x32_f16(af0, bq[kk][0], acc[0][0], 0, 0, 0);
      acc[0][1] = __builtin_amdgcn_mfma_f32_16x16x32_f16(af0, bq[kk][1], acc[0][1], 0, 0, 0);
      acc[1][0] = __builtin_amdgcn_mfma_f32_16x16x32_f16(af1, bq[kk][0], acc[1][0], 0, 0, 0);
      acc[1][1] = __builtin_amdgcn_mfma_f32_16x16x32_f16(af1, bq[kk][1], acc[1][1], 0, 0, 0);
      __builtin_amdgcn_s_setprio(0);
    }

    // ---- epilogue: pr[mf][reg] = sum_nf relu(acc+b2)*w3, DPP 16-lane sum ----
    float pr[2][4];
#pragma unroll
    for (int mf = 0; mf < 2; ++mf)
#pragma unroll
      for (int reg = 0; reg < 4; ++reg) {
        float p = fmaxf(acc[mf][0][reg] + b2v[0], 0.f) * w3v[0] +
                  fmaxf(acc[mf][1][reg] + b2v[1], 0.f) * w3v[1];
        p = dpp_ror_add<0x121>(p);
        p = dpp_ror_add<0x122>(p);
        p = dpp_ror_add<0x124>(p);
        p = dpp_ror_add<0x128>(p);
        pr[mf][reg] = p;  // all 16 lanes hold the col-sum for row (mf, 4*l4+reg)
      }

    // ---- select: lane takes pr[(l15>>2)&1][l15&3]; l15 and l15+8 dup ----
    {
      const float a0 = (l15 & 1) ? pr[0][1] : pr[0][0];
      const float a1 = (l15 & 1) ? pr[0][3] : pr[0][2];
      const float a2 = (l15 & 1) ? pr[1][1] : pr[1][0];
      const float a3 = (l15 & 1) ? pr[1][3] : pr[1][2];
      const float c0 = (l15 & 2) ? a1 : a0;
      const float c1 = (l15 & 2) ? a3 : a2;
      const float v = (l15 & 4) ? c1 : c0;
      const int row64 = rh * 32 + ((l15 >> 2) & 1) * 16 + l4 * 4 + (l15 & 3);
      red[(cq * 8 + g) * 64 + row64] = v;
    }
  }

  __syncthreads();  // all red written

  // ---- final: thread t<512 -> (g = t>>6, j = t&63), sum 8 col-slices ----
  if (tid < 512) {
    const int g = tid >> 6;
    const int j = tid & 63;
    float s = b3v;
#pragma unroll
    for (int c = 0; c < 8; ++c) s += red[(c * 8 + g) * 64 + j];
    out[(i0 + g) * 512 + j0 + j] = s;
  }
}

extern "C" void kernel_launch(void* const* d_in, const int* in_sizes, int n_in,
                              void* d_out, int out_size, void* d_ws, size_t ws_size,
                              hipStream_t stream) {
  const float* x  = (const float*)d_in[0];
  const float* y  = (const float*)d_in[1];
  const float* W1 = (const float*)d_in[2];
  const float* b1 = (const float*)d_in[3];
  const float* W2 = (const float*)d_in[4];
  const float* b2 = (const float*)d_in[5];
  const float* W3 = (const float*)d_in[6];
  const float* b3 = (const float*)d_in[7];
  float* out = (float*)d_out;

  char* ws = (char*)d_ws;
  unsigned int* hx2  = (unsigned int*)ws;              // 512*128*4 = 262144 B
  unsigned int* hy2  = (unsigned int*)(ws + 262144);   // 262144 B
  unsigned int* W2T2 = (unsigned int*)(ws + 524288);   // 131072 B

  k_pre<<<384, 256, 0, stream>>>(x, y, W1, b1, W2, hx2, hy2, W2T2);
  k_main<<<512, 1024, 0, stream>>>(hx2, hy2, W2T2, b2, W3, b3, out);
}